// Round 3
// baseline (127.094 us; speedup 1.0000x reference)
//
#include <hip/hip_runtime.h>

// Spread: out[b,m] = sum_{j=0..2} x[b,m-j] * W[m,m-j] * (1+bias[m])^p(j,m)
// p = j+1 - max(0, m-(N_IN-1)); terms dropped when m-j outside [0,N_IN).
// (Scan unrolled: column m is touched by steps n=m-2,m-1,m; each touch
//  multiplies previously-accumulated terms by s=1+bias[m] once.)
//
// Single fused kernel: per-thread coefficients computed inline (6 scattered
// weight-diagonal loads, L2-absorbed), then 16 coalesced float2 rows.
// Row stride 4098 floats = 16392 B (8 mod 16) -> float2 is the widest
// legal vector; float4 would be misaligned on odd rows.

constexpr int N_IN  = 4096;
constexpr int N_OUT = 4098;
constexpr int BATCH = 2048;
constexpr int ROWS  = 16;   // batch rows per thread (amortize coeff loads)

typedef float v2f __attribute__((ext_vector_type(2)));   // NT-store compatible

__global__ __launch_bounds__(256) void spread_fused(
    const float* __restrict__ x, const float* __restrict__ weight,
    const float* __restrict__ bias, float* __restrict__ out) {
  int pair = blockIdx.x * blockDim.x + threadIdx.x;
  if (pair >= N_OUT / 2) return;               // 2049 pairs
  int m0 = pair * 2;

  // Coefficients for the two columns this thread owns.
  float c00, c10, c20, c01, c11, c21;
  {
    float ctmp[2][3];
#pragma unroll
    for (int k = 0; k < 2; ++k) {
      int m = m0 + k;
      float s  = 1.0f + bias[m];
      float s2 = s * s;
      int red = (m > N_IN - 1) ? (m - (N_IN - 1)) : 0;   // 0,1,2 at tail
#pragma unroll
      for (int j = 0; j < 3; ++j) {
        int n = m - j;
        float cj = 0.0f;
        if (n >= 0 && n < N_IN) {
          int p = j + 1 - red;                 // in {1,2,3} when valid
          float sp = (p == 1) ? s : ((p == 2) ? s2 : s2 * s);
          cj = weight[(size_t)m * N_IN + n] * sp;
        }
        ctmp[k][j] = cj;
      }
    }
    c00 = ctmp[0][0]; c10 = ctmp[0][1]; c20 = ctmp[0][2];
    c01 = ctmp[1][0]; c11 = ctmp[1][1]; c21 = ctmp[1][2];
  }

  // x window: x[m0-2..m0+1], clamped to even bases; clamped lanes always
  // multiply a coefficient that is exactly 0.
  int lo_i = (m0 >= 2) ? (m0 - 2) : 0;
  int hi_i = (m0 <= N_IN - 2) ? m0 : (N_IN - 2);

  int b0 = blockIdx.y * ROWS;
#pragma unroll
  for (int r = 0; r < ROWS; ++r) {
    int b = b0 + r;
    const float* xrow = x + (size_t)b * N_IN;
    v2f lo = *(const v2f*)(xrow + lo_i);   // {x[m0-2], x[m0-1]}
    v2f hi = *(const v2f*)(xrow + hi_i);   // {x[m0],   x[m0+1]}
    float o0 = c00 * hi.x + c10 * lo.y + c20 * lo.x;
    float o1 = c01 * hi.y + c11 * hi.x + c21 * lo.y;
    v2f res; res.x = o0; res.y = o1;
    v2f* dst = (v2f*)(out + (size_t)b * N_OUT + m0);
    __builtin_nontemporal_store(res, dst);
  }
}

extern "C" void kernel_launch(void* const* d_in, const int* in_sizes, int n_in,
                              void* d_out, int out_size, void* d_ws, size_t ws_size,
                              hipStream_t stream) {
  const float* x    = (const float*)d_in[0];
  const float* w    = (const float*)d_in[1];
  const float* bias = (const float*)d_in[2];
  float* out = (float*)d_out;

  dim3 grid((N_OUT / 2 + 255) / 256, BATCH / ROWS);  // (9, 128) = 1152 blocks
  spread_fused<<<grid, dim3(256), 0, stream>>>(x, w, bias, out);
}